// Round 8
// baseline (438.885 us; speedup 1.0000x reference)
//
#include <hip/hip_runtime.h>
#include <hip/hip_bf16.h>
#include <cstdint>

#define N_NODES 100000
#define N_EDGES 1600000
#define N_GRAPHS 64
#define IN_DIM 256
#define HD1 128
#define HD2 256
#define OUT_DIM 512

// CSR-build radix partition parameters
#define NBUCK 196          // ceil(100000/512) buckets of 512 dst nodes
#define NBLK  196          // edge-chunk blocks
#define EPB   8192         // edges per block (NBLK*EPB >= N_EDGES)

typedef __bf16 bf16x8 __attribute__((ext_vector_type(8)));
typedef float f32x4 __attribute__((ext_vector_type(4)));
typedef uint32_t u32x4 __attribute__((ext_vector_type(4)));

static __device__ __forceinline__ float bflo(uint32_t v) { return __uint_as_float(v << 16); }
static __device__ __forceinline__ float bfhi(uint32_t v) { return __uint_as_float(v & 0xffff0000u); }
static __device__ __forceinline__ uint32_t f2bf_bits(float f) {
    uint32_t u = __float_as_uint(f);
    return (u + 0x7fffu + ((u >> 16) & 1u)) >> 16;   // RNE
}
static __device__ __forceinline__ uint32_t packbf(float a, float b) {
    return f2bf_bits(a) | (f2bf_bits(b) << 16);
}
static __device__ __forceinline__ float bf2f(uint16_t b) { return __uint_as_float(((uint32_t)b) << 16); }

// direct global->LDS 16B copy (no VGPR round-trip); lds dest is wave-uniform
// base + lane*16 (we pass the per-lane address; HW takes lane0's base).
static __device__ __forceinline__ void gl_lds16(const void* g, void* l) {
    __builtin_amdgcn_global_load_lds((const __attribute__((address_space(1))) uint32_t*)g,
                                     (__attribute__((address_space(3))) uint32_t*)l, 16, 0, 0);
}

// ---------------- runtime dtype probe ----------------
__global__ void k_probe(const uint32_t* __restrict__ xw, const int* __restrict__ ei,
                        int* __restrict__ flags) {
    if (threadIdx.x != 0 || blockIdx.x != 0) return;
    int mid = 0;
    for (int i = 0; i < 64; i++) {
        uint32_t f = (xw[i] >> 23) & 0xFF;
        if (f >= 64 && f < 200) mid++;
    }
    flags[0] = (mid < 32) ? 1 : 0;                  // bf16 vs f32
    int nz = 0;
    for (int i = 0; i < 64; i++) if (ei[2 * i + 1] != 0) nz++;
    flags[1] = (nz == 0) ? 1 : 0;                   // int64 vs int32
}

static __device__ __forceinline__ int ld_idx(const int* p, int i, int sh) { return p[i << sh]; }
static __device__ __forceinline__ float ld_f(const void* p, int i, int isbf) {
    return isbf ? bf2f(((const uint16_t*)p)[i]) : ((const float*)p)[i];
}

// ---------------- fused weight/bias canonicalization (bf16) ----------------
// W1/W2 packed into per-wave MFMA fragment order: each B-fragment load in the
// GEMMs is a single fully-coalesced 1KB segment (L2-hot, shared by all blocks):
//   W1F[(((n0g*8+ks)*2+nt)*64 + lane)*8 + j] = W1[k][n]
//     k = ks*32 + (lane>>4)*8 + j, n = n0g*32 + nt*16 + (lane&15)   (n0g<4, ks<8)
//   W2F[(((n0g*4+ks)*2+nt)*64 + lane)*8 + j] = W2[k][n]
//     k = ks*32 + (lane>>4)*8 + j, n = n0g*32 + nt*16 + (lane&15)   (n0g<8, ks<4)
__global__ __launch_bounds__(256) void k_prep(const void* __restrict__ W1, const void* __restrict__ W2,
                                              const void* __restrict__ fcW, const void* __restrict__ b1,
                                              const void* __restrict__ b2, const void* __restrict__ fcb,
                                              uint16_t* __restrict__ W1F, uint16_t* __restrict__ W2F,
                                              uint16_t* __restrict__ fcWc, uint16_t* __restrict__ bc1,
                                              uint16_t* __restrict__ bc2, uint16_t* __restrict__ fcbc,
                                              const int* __restrict__ flags) {
    int i = blockIdx.x * 256 + threadIdx.x;
    int isbf = flags[0];
    if (i < 32768) {                                   // W1F packed fragments
        int j = i & 7, l = (i >> 3) & 63, nt = (i >> 9) & 1, ks = (i >> 10) & 7, n0g = (i >> 13) & 3;
        int k = ks * 32 + (l >> 4) * 8 + j;
        int n = n0g * 32 + nt * 16 + (l & 15);
        W1F[i] = (uint16_t)f2bf_bits(ld_f(W1, k * HD1 + n, isbf));
    } else if (i < 65536) {                            // W2F packed fragments
        int j2 = i - 32768;
        int j = j2 & 7, l = (j2 >> 3) & 63, nt = (j2 >> 9) & 1, ks = (j2 >> 10) & 3, n0g = (j2 >> 12) & 7;
        int k = ks * 32 + (l >> 4) * 8 + j;
        int n = n0g * 32 + nt * 16 + (l & 15);
        W2F[j2] = (uint16_t)f2bf_bits(ld_f(W2, k * HD2 + n, isbf));
    } else if (i < 196608) {
        int j = i - 65536;
        fcWc[j] = (uint16_t)f2bf_bits(ld_f(fcW, j, isbf));
    } else if (i < 196736) {
        bc1[i - 196608] = (uint16_t)f2bf_bits(ld_f(b1, i - 196608, isbf));
    } else if (i < 196992) {
        bc2[i - 196736] = (uint16_t)f2bf_bits(ld_f(b2, i - 196736, isbf));
    } else if (i < 197504) {
        fcbc[i - 196992] = (uint16_t)f2bf_bits(ld_f(fcb, i - 196992, isbf));
    }
}

// ---------------- CSR build: atomic-free radix partition by dst bucket ----------------

__global__ __launch_bounds__(256) void k_hist(const int* __restrict__ ei, int* __restrict__ bh,
                                              const int* __restrict__ flags) {
    __shared__ int h[NBUCK];
    int t = threadIdx.x, blk = blockIdx.x;
    if (t < NBUCK) h[t] = 0;
    __syncthreads();
    int sh = flags[1];
    int base = blk * EPB;
#pragma unroll
    for (int k = 0; k < EPB / 256; k++) {
        int e = base + k * 256 + t;
        if (e < N_EDGES) atomicAdd(&h[ld_idx(ei, N_EDGES + e, sh) >> 9], 1);
    }
    __syncthreads();
    if (t < NBUCK) bh[blk * NBUCK + t] = h[t];
}

__global__ __launch_bounds__(256) void k_colscan(const int* __restrict__ bh, int* __restrict__ bhoff,
                                                 int* __restrict__ bucket_cnt) {
    __shared__ int s[256];
    int b = blockIdx.x, t = threadIdx.x;
    int v = (t < NBLK) ? bh[t * NBUCK + b] : 0;
    s[t] = v; __syncthreads();
    for (int off = 1; off < 256; off <<= 1) {
        int x = (t >= off) ? s[t - off] : 0;
        __syncthreads();
        s[t] += x;
        __syncthreads();
    }
    if (t < NBLK) bhoff[t * NBUCK + b] = s[t] - v;    // exclusive within bucket
    if (t == 255) bucket_cnt[b] = s[255];
}

__global__ __launch_bounds__(256) void k_bscan(const int* __restrict__ bucket_cnt,
                                               int* __restrict__ bucket_base,
                                               int* __restrict__ row_ptr) {
    __shared__ int s[256];
    int t = threadIdx.x;
    int v = (t < NBUCK) ? bucket_cnt[t] : 0;
    s[t] = v; __syncthreads();
    for (int off = 1; off < 256; off <<= 1) {
        int x = (t >= off) ? s[t - off] : 0;
        __syncthreads();
        s[t] += x;
        __syncthreads();
    }
    if (t < NBUCK) bucket_base[t] = s[t] - v;
    if (t == NBUCK - 1) { bucket_base[NBUCK] = s[t]; row_ptr[N_NODES] = s[t]; }
}

__global__ __launch_bounds__(256) void k_part(const int* __restrict__ ei,
                                              const int* __restrict__ bucket_base,
                                              const int* __restrict__ bhoff,
                                              int* __restrict__ tmp,
                                              const int* __restrict__ flags) {
    __shared__ int cur[NBUCK];
    int t = threadIdx.x, blk = blockIdx.x;
    if (t < NBUCK) cur[t] = bucket_base[t] + bhoff[blk * NBUCK + t];
    __syncthreads();
    int sh = flags[1];
    int base = blk * EPB;
#pragma unroll
    for (int k = 0; k < EPB / 256; k++) {
        int e = base + k * 256 + t;
        if (e < N_EDGES) {
            int s = ld_idx(ei, e, sh), d = ld_idx(ei, N_EDGES + e, sh);
            int pos = atomicAdd(&cur[d >> 9], 1);
            tmp[pos] = (s << 9) | (d & 511);          // s<2^17 -> 26-bit key
        }
    }
}

__global__ __launch_bounds__(256) void k_bsort(const int* __restrict__ tmp,
                                               const int* __restrict__ bucket_base,
                                               int* __restrict__ csr_src,
                                               int* __restrict__ row_ptr,
                                               float* __restrict__ dinv) {
    __shared__ int h[512], a[512], c[512];
    int b = blockIdx.x, t = threadIdx.x;
    int beg = bucket_base[b], end = bucket_base[b + 1];
    h[t] = 0; h[t + 256] = 0;
    __syncthreads();
    for (int i = beg + t; i < end; i += 256) atomicAdd(&h[tmp[i] & 511], 1);
    __syncthreads();
    a[t] = h[t]; a[t + 256] = h[t + 256];
    __syncthreads();
    for (int off = 1; off < 512; off <<= 1) {
        int x0 = (t >= off) ? a[t - off] : 0;
        int x1 = ((t + 256) >= off) ? a[t + 256 - off] : 0;
        __syncthreads();
        a[t] += x0; a[t + 256] += x1;
        __syncthreads();
    }
#pragma unroll
    for (int u = 0; u < 2; u++) {
        int i = t + u * 256;
        int node = (b << 9) + i;
        int ex = a[i] - h[i];
        if (node < N_NODES) {
            row_ptr[node] = beg + ex;
            dinv[node] = rsqrtf((float)(h[i] + 1));   // +1 self-loop
        }
        c[i] = ex;
    }
    __syncthreads();
    for (int i = beg + t; i < end; i += 256) {
        int e = tmp[i];
        int pos = atomicAdd(&c[e & 511], 1);
        csr_src[beg + pos] = e >> 9;
    }
}

// ---------------- pack per-edge (src, dinv[src]) for the agg kernels ----------------
// dinv is L2-resident (400 KB); one gather here removes the random dinv gather
// from BOTH agg passes.
__global__ __launch_bounds__(256) void k_wpack(const int* __restrict__ csr_src,
                                               const float* __restrict__ dinv,
                                               int2* __restrict__ csr_sw) {
    int e = blockIdx.x * 256 + threadIdx.x;
    if (e < N_EDGES) {
        int s = csr_src[e];
        csr_sw[e] = make_int2(s, __float_as_int(dinv[s]));
    }
}

// ---------------- per-graph node counts ----------------
#define GCNT_CHUNK 8
__global__ __launch_bounds__(256) void k_gcnt(const int* __restrict__ bat, int* __restrict__ gcnt,
                                              const int* __restrict__ flags) {
    __shared__ int h[N_GRAPHS];
    int t = threadIdx.x;
    if (t < N_GRAPHS) h[t] = 0;
    __syncthreads();
    int sh = flags[1];
    int base = (blockIdx.x * 256 + t) * GCNT_CHUNK;
    int cur = -1, run = 0;
#pragma unroll
    for (int u = 0; u < GCNT_CHUNK; u++) {
        int i = base + u;
        if (i < N_NODES) {
            int g = ld_idx(bat, i, sh);
            if (g == cur) run++;
            else { if (run) atomicAdd(&h[cur], run); cur = g; run = 1; }
        }
    }
    if (run) atomicAdd(&h[cur], run);
    __syncthreads();
    if (t < N_GRAPHS) { int v = h[t]; if (v) atomicAdd(&gcnt[t], v); }
}

// ---------------- GEMM-1: Y1[M,128] = X[M,256] @ W1 ----------------
// Block = 64 rows x FULL 128 cols (A read exactly once -> FETCH = ideal).
// A: one-shot global_load_lds stage (no VGPR round-trip), XOR-swizzled via
// pre-swizzled SOURCE address (linear LDS dest; rule: both-sides-or-neither).
// B: per-wave 32 cols register-resident, 16 x 1KB coalesced packed loads.
// One barrier total; stage latency hidden by 3+ independent blocks/CU.

__global__ __launch_bounds__(256) void k_gemm1(const void* __restrict__ Ain,
                                               const uint16_t* __restrict__ BF,  // W1F packed
                                               uint16_t* __restrict__ C,
                                               const int* __restrict__ flags) {
    __shared__ __align__(16) uint16_t As[64 * 256];   // 32 KB, swizzled, 16B-aligned
    const int M = N_NODES, N = HD1;
    int isbf = flags[0];
    int t = threadIdx.x;
    int wave = t >> 6, lane = t & 63;
    int quad = lane >> 4, l16 = lane & 15;
    int m0 = blockIdx.x * 64;
    int n0 = wave * 32;                               // wave's col group (n0g = wave)

    // B fragments: 16 x 1KB coalesced (L2-hot), issued before the stage
    bf16x8 Bf[8][2];
#pragma unroll
    for (int ks = 0; ks < 8; ks++)
#pragma unroll
        for (int nt = 0; nt < 2; nt++)
            Bf[ks][nt] = *(const bf16x8*)(BF + ((((wave * 8 + ks) * 2 + nt) << 6) + lane) * 8);

    // A-tile stage: 32 KB = 8 x (256 threads x 16B). LDS byte o holds logical
    // (r, c) with c = (o&511) ^ ((r&7)<<4)  -> read side applies the same XOR.
    if (isbf) {
        const uint8_t* Xb = (const uint8_t*)Ain;
#pragma unroll
        for (int i = 0; i < 8; i++) {
            int o = (i * 256 + t) * 16;
            int r = o >> 9, c = o & 511;
            int rg = m0 + r; if (rg >= M) rg = M - 1;
            gl_lds16(Xb + (size_t)rg * 512 + (c ^ ((r & 7) << 4)), (uint8_t*)As + o);
        }
    } else {
        const float* Xf = (const float*)Ain;
#pragma unroll
        for (int i = 0; i < 8; i++) {
            int o = (i * 256 + t) * 16;
            int r = o >> 9, c = (o & 511) ^ ((r & 7) << 4);
            int rg = m0 + r; if (rg >= M) rg = M - 1;
            const float* p = Xf + (size_t)rg * 256 + (c >> 1);
            f32x4 f0 = *(const f32x4*)p, f1 = *(const f32x4*)(p + 4);
            union { uint16_t u[8]; bf16x8 v; } rr;
#pragma unroll
            for (int j = 0; j < 4; j++) {
                rr.u[j]     = (uint16_t)f2bf_bits(f0[j]);
                rr.u[4 + j] = (uint16_t)f2bf_bits(f1[j]);
            }
            *(bf16x8*)((uint8_t*)As + o) = rr.v;
        }
    }
    __syncthreads();

    f32x4 acc[4][2];
#pragma unroll
    for (int a = 0; a < 4; a++)
#pragma unroll
        for (int b = 0; b < 2; b++) acc[a][b] = f32x4{0.f, 0.f, 0.f, 0.f};

#pragma unroll
    for (int ks = 0; ks < 8; ks++) {
        bf16x8 af[4];
#pragma unroll
        for (int mt = 0; mt < 4; mt++) {
            int r = mt * 16 + l16;
            int cb = (ks * 64 + quad * 16) ^ ((r & 7) << 4);
            af[mt] = *(const bf16x8*)((const uint8_t*)As + r * 512 + cb);
        }
#pragma unroll
        for (int mt = 0; mt < 4; mt++)
#pragma unroll
            for (int nt = 0; nt < 2; nt++)
                acc[mt][nt] = __builtin_amdgcn_mfma_f32_16x16x32_bf16(af[mt], Bf[ks][nt], acc[mt][nt], 0, 0, 0);
    }

#pragma unroll
    for (int mt = 0; mt < 4; mt++)
#pragma unroll
        for (int reg = 0; reg < 4; reg++) {
            int row = m0 + mt * 16 + quad * 4 + reg;  // C/D: col=lane&15, row=quad*4+reg
            if (row < M)
#pragma unroll
                for (int nt = 0; nt < 2; nt++)
                    C[row * N + n0 + nt * 16 + l16] = (uint16_t)f2bf_bits(acc[mt][nt][reg]);
        }
}

// ---------------- aggregation (4 edges per gather instruction, 16B/lane) ----------------
// out[d] = dinv[d] * (sum_src w_s*Y[s] + dinv[d]*Y[d]) [+bias, relu],  w_s = dinv[src]
// Lane l covers edge (l>>4) of each quartet at 16B row-chunk (l&15): one
// global_load_dwordx4 moves 1KB (4 rows) -> 4x bytes-in-flight vs 4B/lane.
// Broadcast via v_readlane at UNIFORM indices + cndmask select by group (the
// R5-verified primitive; no ds_bpermute in the hot loop). 16-edge macro-rounds
// keep 4 dwordx4 gathers in flight. Lane-group partials merged by one
// shfl_xor(16/32) tree at the end (fp32 reorder, within tolerance).

template <int WITH_BIAS_RELU>
__global__ __launch_bounds__(256) void k_agg(const uint16_t* __restrict__ Yin, uint16_t* __restrict__ Yout,
                                             const int* __restrict__ row_ptr, const int2* __restrict__ csr_sw,
                                             const float* __restrict__ dinv, const uint16_t* __restrict__ bias) {
    int node = blockIdx.x * 4 + (threadIdx.x >> 6);
    int l = threadIdx.x & 63;
    int grp = l >> 4;                                  // which edge of the quartet
    int c16 = l & 15;                                  // 16B chunk within row
    const u32x4* Y4 = (const u32x4*)Yin;               // row = 16 chunks of 16B

    float wd = dinv[node];
    float a[8];
    {   // self-loop: only group 0 contributes (others would quadruple it)
        u32x4 v = Y4[(size_t)node * 16 + c16];
        float w = (grp == 0) ? wd : 0.f;
#pragma unroll
        for (int j = 0; j < 4; j++) {
            a[2 * j]     = w * bflo(v[j]);
            a[2 * j + 1] = w * bfhi(v[j]);
        }
    }

    int e0 = row_ptr[node], e1 = row_ptr[node + 1];
    for (int cb = e0; cb < e1; cb += 64) {
        int cnt = e1 - cb; if (cnt > 64) cnt = 64;
        int my_s = 0, my_w = 0;                        // lanes >= cnt: w=0 -> contribute 0, read row 0
        if (l < cnt) { int2 sw = csr_sw[cb + l]; my_s = sw.x; my_w = sw.y; }
        int mrounds = (cnt + 15) >> 4;                 // 16 edges per macro-round
        for (int r = 0; r < mrounds; r++) {
            u32x4 vv[4];
            float ww[4];
#pragma unroll
            for (int q = 0; q < 4; q++) {
                int base = r * 16 + q * 4;             // uniform; base+3 <= 63
                int s0 = __builtin_amdgcn_readlane(my_s, base + 0);
                int s1 = __builtin_amdgcn_readlane(my_s, base + 1);
                int s2 = __builtin_amdgcn_readlane(my_s, base + 2);
                int s3 = __builtin_amdgcn_readlane(my_s, base + 3);
                int w0 = __builtin_amdgcn_readlane(my_w, base + 0);
                int w1 = __builtin_amdgcn_readlane(my_w, base + 1);
                int w2 = __builtin_amdgcn_readlane(my_w, base + 2);
                int w3 = __builtin_amdgcn_readlane(my_w, base + 3);
                int s = (grp == 0) ? s0 : (grp == 1) ? s1 : (grp == 2) ? s2 : s3;
                int w = (grp == 0) ? w0 : (grp == 1) ? w1 : (grp == 2) ? w2 : w3;
                ww[q] = __uint_as_float((uint32_t)w);
                vv[q] = Y4[(size_t)s * 16 + c16];
            }
#pragma unroll
            for (int q = 0; q < 4; q++)
#pragma unroll
                for (int j = 0; j < 4; j++) {
                    a[2 * j]     += ww[q] * bflo(vv[q][j]);
                    a[2 * j + 1] += ww[q] * bfhi(vv[q][j]);
                }
        }
    }

    // merge the 4 edge-group partials (lanes l, l^16, l^32, l^48)
#pragma unroll
    for (int j = 0; j < 8; j++) {
        a[j] += __shfl_xor(a[j], 16);
        a[j] += __shfl_xor(a[j], 32);
    }

    if (grp == 0) {                                    // 16 lanes x 16B = 256B row store
        uint32_t o[4];
#pragma unroll
        for (int j = 0; j < 4; j++) {
            float x0 = a[2 * j] * wd, x1 = a[2 * j + 1] * wd;
            if (WITH_BIAS_RELU) {
                x0 = fmaxf(x0 + bf2f(bias[c16 * 8 + 2 * j]), 0.f);
                x1 = fmaxf(x1 + bf2f(bias[c16 * 8 + 2 * j + 1]), 0.f);
            }
            o[j] = packbf(x0, x1);
        }
        *(u32x4*)((uint32_t*)Yout + (size_t)node * 64 + c16 * 4) = u32x4{o[0], o[1], o[2], o[3]};
    }
}

// ---------------- GEMM-2 + fused bias/relu/pool: pooled[g] += relu(Z@W2 + b2) ----------------
// Same structure as k_gemm1: block = 64 rows x FULL 256 cols (A staged once),
// 8 waves x 32 cols, register-resident packed B, swizzled LDS A-tile.

__global__ __launch_bounds__(512) void k_gemm2_pool(const uint16_t* __restrict__ A,   // Zb [M][128]
                                                    const uint16_t* __restrict__ BF,  // W2F packed
                                                    const uint16_t* __restrict__ bias,// bc2 [256]
                                                    const int* __restrict__ bat,
                                                    const int* __restrict__ flags,
                                                    float* __restrict__ pooled) {
    __shared__ __align__(16) uint16_t As[64 * 128];   // 16 KB, swizzled, 16B-aligned
    const int M = N_NODES;
    int t = threadIdx.x;
    int wave = t >> 6, lane = t & 63;
    int quad = lane >> 4, l16 = lane & 15;
    int m0 = blockIdx.x * 64;
    int n0 = wave * 32;                               // 8 waves x 32 cols = 256

    bf16x8 Bf[4][2];
#pragma unroll
    for (int ks = 0; ks < 4; ks++)
#pragma unroll
        for (int nt = 0; nt < 2; nt++)
            Bf[ks][nt] = *(const bf16x8*)(BF + ((((wave * 4 + ks) * 2 + nt) << 6) + lane) * 8);

    // A-tile stage: 16 KB = 2 x (512 threads x 16B); Zb is always bf16
#pragma unroll
    for (int i = 0; i < 2; i++) {
        int o = (i * 512 + t) * 16;
        int r = o >> 8, c = o & 255;
        int rg = m0 + r; if (rg >= M) rg = M - 1;
        gl_lds16((const uint8_t*)A + (size_t)rg * 256 + (c ^ ((r & 7) << 4)), (uint8_t*)As + o);
    }
    __syncthreads();

    f32x4 acc[4][2];
#pragma unroll
    for (int a = 0; a < 4; a++)
#pragma unroll
        for (int b = 0; b < 2; b++) acc[a][b] = f32x4{0.f, 0.f, 0.f, 0.f};

#pragma unroll
    for (int ks = 0; ks < 4; ks++) {
        bf16x8 af[4];
#pragma unroll
        for (int mt = 0; mt < 4; mt++) {
            int r = mt * 16 + l16;
            int cb = (ks * 64 + quad * 16) ^ ((r & 7) << 4);
            af[mt] = *(const bf16x8*)((const uint8_t*)As + r * 256 + cb);
        }
#pragma unroll
        for (int mt = 0; mt < 4; mt++)
#pragma unroll
            for (int nt = 0; nt < 2; nt++)
                acc[mt][nt] = __builtin_amdgcn_mfma_f32_16x16x32_bf16(af[mt], Bf[ks][nt], acc[mt][nt], 0, 0, 0);
    }

    int sh = flags[1];
    float bv[2];
#pragma unroll
    for (int nt = 0; nt < 2; nt++) bv[nt] = bf2f(bias[n0 + nt * 16 + l16]);

    int last = m0 + 63 < M ? m0 + 63 : M - 1;
    int gfirst = ld_idx(bat, m0, sh);
    int glast  = ld_idx(bat, last, sh);
    if ((m0 + 63 < M) && gfirst == glast) {
        // all 64 rows valid, same graph: wave-local reduction, 1 atomic/col
#pragma unroll
        for (int nt = 0; nt < 2; nt++) {
            float s = 0.f;
#pragma unroll
            for (int mt = 0; mt < 4; mt++)
#pragma unroll
                for (int reg = 0; reg < 4; reg++)
                    s += fmaxf(acc[mt][nt][reg] + bv[nt], 0.f);
            s += __shfl_xor(s, 16);
            s += __shfl_xor(s, 32);
            if (quad == 0)
                atomicAdd(&pooled[gfirst * HD2 + n0 + nt * 16 + l16], s);
        }
    } else {
#pragma unroll
        for (int mt = 0; mt < 4; mt++) {
#pragma unroll
            for (int reg = 0; reg < 4; reg++) {
                int row = m0 + mt * 16 + quad * 4 + reg;
                if (row < M) {
                    int g = ld_idx(bat, row, sh);
#pragma unroll
                    for (int nt = 0; nt < 2; nt++)
                        atomicAdd(&pooled[g * HD2 + n0 + nt * 16 + l16],
                                  fmaxf(acc[mt][nt][reg] + bv[nt], 0.f));
                }
            }
        }
    }
}

// ---------------- final FC: out = relu(mean @ fcW + fcb), dual-dtype out ----------------

__global__ __launch_bounds__(512) void k_final(const float* __restrict__ pooled, const int* __restrict__ gcnt,
                                               const uint16_t* __restrict__ fcWc, const uint16_t* __restrict__ fcbc,
                                               void* __restrict__ out, const int* __restrict__ flags) {
    __shared__ float pm[HD2];
    int g = blockIdx.x, t = threadIdx.x;
    if (t < HD2) pm[t] = pooled[g * HD2 + t] / fmaxf((float)gcnt[g], 1.0f);
    __syncthreads();
    float acc = bf2f(fcbc[t]);
    for (int k = 0; k < HD2; k++) acc = fmaf(pm[k], bf2f(fcWc[k * OUT_DIM + t]), acc);
    acc = fmaxf(acc, 0.f);
    if (flags[0]) ((uint16_t*)out)[g * OUT_DIM + t] = (uint16_t)f2bf_bits(acc);
    else          ((float*)out)[g * OUT_DIM + t] = acc;
}

// ---------------- launcher ----------------

extern "C" void kernel_launch(void* const* d_in, const int* in_sizes, int n_in,
                              void* d_out, int out_size, void* d_ws, size_t ws_size,
                              hipStream_t stream) {
    const void* x   = d_in[0];               // [100000,256] bf16 or f32
    const int*  ei  = (const int*)d_in[1];   // [2,1600000] int32 or int64
    const int*  bat = (const int*)d_in[2];   // [100000]
    const void* W1  = d_in[3];               // [256,128]
    const void* b1  = d_in[4];               // [128]
    const void* W2  = d_in[5];               // [128,256]
    const void* b2  = d_in[6];               // [256]
    const void* fcW = d_in[7];               // [256,512]
    const void* fcb = d_in[8];               // [512]

    char* ws = (char*)d_ws;
    size_t off = 0;
    auto alloc = [&](size_t bytes) -> void* {
        void* p = ws + off;
        off += (bytes + 255) & ~(size_t)255;
        return p;
    };
    uint16_t* buf0 = (uint16_t*)alloc((size_t)N_NODES * HD1 * 2);   // Y1, later Zb
    uint16_t* Hb   = (uint16_t*)alloc((size_t)N_NODES * HD1 * 2);
    int*   row_ptr = (int*)alloc((N_NODES + 1) * 4);
    int*   csr_src = (int*)alloc((size_t)N_EDGES * 4);
    int2*  csr_sw  = (int2*)alloc((size_t)N_EDGES * 8);
    int*   tmp     = (int*)alloc((size_t)N_EDGES * 4);
    int*   bh      = (int*)alloc(NBLK * NBUCK * 4);
    int*   bhoff   = (int*)alloc(NBLK * NBUCK * 4);
    int*   bucket_cnt  = (int*)alloc(NBUCK * 4);
    int*   bucket_base = (int*)alloc((NBUCK + 1) * 4);
    float* dinv    = (float*)alloc(N_NODES * 4);
    int*   gcnt    = (int*)alloc(N_GRAPHS * 4);
    float* pooled  = (float*)alloc(N_GRAPHS * HD2 * 4);
    uint16_t* W1T  = (uint16_t*)alloc(IN_DIM * HD1 * 2);
    uint16_t* W2T  = (uint16_t*)alloc(HD1 * HD2 * 2);
    uint16_t* bc1  = (uint16_t*)alloc(HD1 * 2);
    uint16_t* bc2  = (uint16_t*)alloc(HD2 * 2);
    uint16_t* fcWc = (uint16_t*)alloc(HD2 * OUT_DIM * 2);
    uint16_t* fcbc = (uint16_t*)alloc(OUT_DIM * 2);
    int*   flags   = (int*)alloc(64 * 4);

    uint16_t* Y1 = buf0;
    uint16_t* Zb = buf0;   // Y1 dead after agg-1

    hipMemsetAsync(gcnt, 0, N_GRAPHS * 4, stream);
    hipMemsetAsync(pooled, 0, N_GRAPHS * HD2 * 4, stream);

    k_probe<<<1, 64, 0, stream>>>((const uint32_t*)x, ei, flags);

    // canonicalize weights/biases to bf16 (one fused kernel; W1/W2 fragment-packed)
    k_prep<<<(197504 + 255) / 256, 256, 0, stream>>>(W1, W2, fcW, b1, b2, fcb,
                                                     W1T, W2T, fcWc, bc1, bc2, fcbc, flags);

    // CSR build: hist -> colscan -> bscan -> part -> bucket sort (no global atomics)
    k_hist<<<NBLK, 256, 0, stream>>>(ei, bh, flags);
    k_colscan<<<NBUCK, 256, 0, stream>>>(bh, bhoff, bucket_cnt);
    k_bscan<<<1, 256, 0, stream>>>(bucket_cnt, bucket_base, row_ptr);
    k_part<<<NBLK, 256, 0, stream>>>(ei, bucket_base, bhoff, tmp, flags);
    k_bsort<<<NBUCK, 256, 0, stream>>>(tmp, bucket_base, csr_src, row_ptr, dinv);
    k_wpack<<<N_EDGES / 256, 256, 0, stream>>>(csr_src, dinv, csr_sw);

    k_gcnt<<<(N_NODES + 256 * GCNT_CHUNK - 1) / (256 * GCNT_CHUNK), 256, 0, stream>>>(bat, gcnt, flags);

    // layer 1: Y1 = X @ W1 ; H = relu(A Y1 + b1)
    k_gemm1<<<(N_NODES + 63) / 64, 256, 0, stream>>>(x, W1T, Y1, flags);
    k_agg<1><<<N_NODES / 4, 256, 0, stream>>>(Y1, Hb, row_ptr, csr_sw, dinv, bc1);

    // layer 2 (aggregate-first): Z = A H ; pooled += relu(Z @ W2 + b2)
    k_agg<0><<<N_NODES / 4, 256, 0, stream>>>(Hb, Zb, row_ptr, csr_sw, dinv, nullptr);
    k_gemm2_pool<<<(N_NODES + 63) / 64, 512, 0, stream>>>(Zb, W2T, bc2, bat, flags, pooled);

    // final FC
    k_final<<<N_GRAPHS, 512, 0, stream>>>(pooled, gcnt, fcWc, fcbc, d_out, flags);
}

// Round 9
// 419.421 us; speedup vs baseline: 1.0464x; 1.0464x over previous
//
#include <hip/hip_runtime.h>
#include <hip/hip_bf16.h>
#include <cstdint>

#define N_NODES 100000
#define N_EDGES 1600000
#define N_GRAPHS 64
#define IN_DIM 256
#define HD1 128
#define HD2 256
#define OUT_DIM 512

// CSR-build radix partition parameters
#define NBUCK 196          // ceil(100000/512) buckets of 512 dst nodes
#define NBLK  196          // edge-chunk blocks
#define EPB   8192         // edges per block (NBLK*EPB >= N_EDGES)

typedef __bf16 bf16x8 __attribute__((ext_vector_type(8)));
typedef float f32x4 __attribute__((ext_vector_type(4)));

static __device__ __forceinline__ float bflo(uint32_t v) { return __uint_as_float(v << 16); }
static __device__ __forceinline__ float bfhi(uint32_t v) { return __uint_as_float(v & 0xffff0000u); }
static __device__ __forceinline__ uint32_t f2bf_bits(float f) {
    uint32_t u = __float_as_uint(f);
    return (u + 0x7fffu + ((u >> 16) & 1u)) >> 16;   // RNE
}
static __device__ __forceinline__ uint32_t packbf(float a, float b) {
    return f2bf_bits(a) | (f2bf_bits(b) << 16);
}
static __device__ __forceinline__ float bf2f(uint16_t b) { return __uint_as_float(((uint32_t)b) << 16); }

// direct global->LDS 16B copy (no VGPR round-trip); lds dest is wave-uniform
// base + lane*16 (we pass the per-lane address; HW takes lane0's base).
static __device__ __forceinline__ void gl_lds16(const void* g, void* l) {
    __builtin_amdgcn_global_load_lds((const __attribute__((address_space(1))) uint32_t*)g,
                                     (__attribute__((address_space(3))) uint32_t*)l, 16, 0, 0);
}

// ---------------- runtime dtype probe ----------------
__global__ void k_probe(const uint32_t* __restrict__ xw, const int* __restrict__ ei,
                        int* __restrict__ flags) {
    if (threadIdx.x != 0 || blockIdx.x != 0) return;
    int mid = 0;
    for (int i = 0; i < 64; i++) {
        uint32_t f = (xw[i] >> 23) & 0xFF;
        if (f >= 64 && f < 200) mid++;
    }
    flags[0] = (mid < 32) ? 1 : 0;                  // bf16 vs f32
    int nz = 0;
    for (int i = 0; i < 64; i++) if (ei[2 * i + 1] != 0) nz++;
    flags[1] = (nz == 0) ? 1 : 0;                   // int64 vs int32
}

static __device__ __forceinline__ int ld_idx(const int* p, int i, int sh) { return p[i << sh]; }
static __device__ __forceinline__ float ld_f(const void* p, int i, int isbf) {
    return isbf ? bf2f(((const uint16_t*)p)[i]) : ((const float*)p)[i];
}

// ---------------- fused weight/bias canonicalization (bf16) ----------------
// W1/W2 packed into per-wave MFMA fragment order: each B-fragment load in the
// GEMMs is a single fully-coalesced 1KB segment (L2-hot, shared by all blocks):
//   W1F[(((n0g*8+ks)*2+nt)*64 + lane)*8 + j] = W1[k][n]
//     k = ks*32 + (lane>>4)*8 + j, n = n0g*32 + nt*16 + (lane&15)   (n0g<4, ks<8)
//   W2F[(((n0g*4+ks)*2+nt)*64 + lane)*8 + j] = W2[k][n]
//     k = ks*32 + (lane>>4)*8 + j, n = n0g*32 + nt*16 + (lane&15)   (n0g<8, ks<4)
__global__ __launch_bounds__(256) void k_prep(const void* __restrict__ W1, const void* __restrict__ W2,
                                              const void* __restrict__ fcW, const void* __restrict__ b1,
                                              const void* __restrict__ b2, const void* __restrict__ fcb,
                                              uint16_t* __restrict__ W1F, uint16_t* __restrict__ W2F,
                                              uint16_t* __restrict__ fcWc, uint16_t* __restrict__ bc1,
                                              uint16_t* __restrict__ bc2, uint16_t* __restrict__ fcbc,
                                              const int* __restrict__ flags) {
    int i = blockIdx.x * 256 + threadIdx.x;
    int isbf = flags[0];
    if (i < 32768) {                                   // W1F packed fragments
        int j = i & 7, l = (i >> 3) & 63, nt = (i >> 9) & 1, ks = (i >> 10) & 7, n0g = (i >> 13) & 3;
        int k = ks * 32 + (l >> 4) * 8 + j;
        int n = n0g * 32 + nt * 16 + (l & 15);
        W1F[i] = (uint16_t)f2bf_bits(ld_f(W1, k * HD1 + n, isbf));
    } else if (i < 65536) {                            // W2F packed fragments
        int j2 = i - 32768;
        int j = j2 & 7, l = (j2 >> 3) & 63, nt = (j2 >> 9) & 1, ks = (j2 >> 10) & 3, n0g = (j2 >> 12) & 7;
        int k = ks * 32 + (l >> 4) * 8 + j;
        int n = n0g * 32 + nt * 16 + (l & 15);
        W2F[j2] = (uint16_t)f2bf_bits(ld_f(W2, k * HD2 + n, isbf));
    } else if (i < 196608) {
        int j = i - 65536;
        fcWc[j] = (uint16_t)f2bf_bits(ld_f(fcW, j, isbf));
    } else if (i < 196736) {
        bc1[i - 196608] = (uint16_t)f2bf_bits(ld_f(b1, i - 196608, isbf));
    } else if (i < 196992) {
        bc2[i - 196736] = (uint16_t)f2bf_bits(ld_f(b2, i - 196736, isbf));
    } else if (i < 197504) {
        fcbc[i - 196992] = (uint16_t)f2bf_bits(ld_f(fcb, i - 196992, isbf));
    }
}

// ---------------- CSR build: atomic-free radix partition by dst bucket ----------------

__global__ __launch_bounds__(256) void k_hist(const int* __restrict__ ei, int* __restrict__ bh,
                                              const int* __restrict__ flags) {
    __shared__ int h[NBUCK];
    int t = threadIdx.x, blk = blockIdx.x;
    if (t < NBUCK) h[t] = 0;
    __syncthreads();
    int sh = flags[1];
    int base = blk * EPB;
#pragma unroll
    for (int k = 0; k < EPB / 256; k++) {
        int e = base + k * 256 + t;
        if (e < N_EDGES) atomicAdd(&h[ld_idx(ei, N_EDGES + e, sh) >> 9], 1);
    }
    __syncthreads();
    if (t < NBUCK) bh[blk * NBUCK + t] = h[t];
}

__global__ __launch_bounds__(256) void k_colscan(const int* __restrict__ bh, int* __restrict__ bhoff,
                                                 int* __restrict__ bucket_cnt) {
    __shared__ int s[256];
    int b = blockIdx.x, t = threadIdx.x;
    int v = (t < NBLK) ? bh[t * NBUCK + b] : 0;
    s[t] = v; __syncthreads();
    for (int off = 1; off < 256; off <<= 1) {
        int x = (t >= off) ? s[t - off] : 0;
        __syncthreads();
        s[t] += x;
        __syncthreads();
    }
    if (t < NBLK) bhoff[t * NBUCK + b] = s[t] - v;    // exclusive within bucket
    if (t == 255) bucket_cnt[b] = s[255];
}

__global__ __launch_bounds__(256) void k_bscan(const int* __restrict__ bucket_cnt,
                                               int* __restrict__ bucket_base,
                                               int* __restrict__ row_ptr) {
    __shared__ int s[256];
    int t = threadIdx.x;
    int v = (t < NBUCK) ? bucket_cnt[t] : 0;
    s[t] = v; __syncthreads();
    for (int off = 1; off < 256; off <<= 1) {
        int x = (t >= off) ? s[t - off] : 0;
        __syncthreads();
        s[t] += x;
        __syncthreads();
    }
    if (t < NBUCK) bucket_base[t] = s[t] - v;
    if (t == NBUCK - 1) { bucket_base[NBUCK] = s[t]; row_ptr[N_NODES] = s[t]; }
}

__global__ __launch_bounds__(256) void k_part(const int* __restrict__ ei,
                                              const int* __restrict__ bucket_base,
                                              const int* __restrict__ bhoff,
                                              int* __restrict__ tmp,
                                              const int* __restrict__ flags) {
    __shared__ int cur[NBUCK];
    int t = threadIdx.x, blk = blockIdx.x;
    if (t < NBUCK) cur[t] = bucket_base[t] + bhoff[blk * NBUCK + t];
    __syncthreads();
    int sh = flags[1];
    int base = blk * EPB;
#pragma unroll
    for (int k = 0; k < EPB / 256; k++) {
        int e = base + k * 256 + t;
        if (e < N_EDGES) {
            int s = ld_idx(ei, e, sh), d = ld_idx(ei, N_EDGES + e, sh);
            int pos = atomicAdd(&cur[d >> 9], 1);
            tmp[pos] = (s << 9) | (d & 511);          // s<2^17 -> 26-bit key
        }
    }
}

__global__ __launch_bounds__(256) void k_bsort(const int* __restrict__ tmp,
                                               const int* __restrict__ bucket_base,
                                               int* __restrict__ csr_src,
                                               int* __restrict__ row_ptr,
                                               float* __restrict__ dinv) {
    __shared__ int h[512], a[512], c[512];
    int b = blockIdx.x, t = threadIdx.x;
    int beg = bucket_base[b], end = bucket_base[b + 1];
    h[t] = 0; h[t + 256] = 0;
    __syncthreads();
    for (int i = beg + t; i < end; i += 256) atomicAdd(&h[tmp[i] & 511], 1);
    __syncthreads();
    a[t] = h[t]; a[t + 256] = h[t + 256];
    __syncthreads();
    for (int off = 1; off < 512; off <<= 1) {
        int x0 = (t >= off) ? a[t - off] : 0;
        int x1 = ((t + 256) >= off) ? a[t + 256 - off] : 0;
        __syncthreads();
        a[t] += x0; a[t + 256] += x1;
        __syncthreads();
    }
#pragma unroll
    for (int u = 0; u < 2; u++) {
        int i = t + u * 256;
        int node = (b << 9) + i;
        int ex = a[i] - h[i];
        if (node < N_NODES) {
            row_ptr[node] = beg + ex;
            dinv[node] = rsqrtf((float)(h[i] + 1));   // +1 self-loop
        }
        c[i] = ex;
    }
    __syncthreads();
    for (int i = beg + t; i < end; i += 256) {
        int e = tmp[i];
        int pos = atomicAdd(&c[e & 511], 1);
        csr_src[beg + pos] = e >> 9;
    }
}

// ---------------- per-graph node counts ----------------
#define GCNT_CHUNK 8
__global__ __launch_bounds__(256) void k_gcnt(const int* __restrict__ bat, int* __restrict__ gcnt,
                                              const int* __restrict__ flags) {
    __shared__ int h[N_GRAPHS];
    int t = threadIdx.x;
    if (t < N_GRAPHS) h[t] = 0;
    __syncthreads();
    int sh = flags[1];
    int base = (blockIdx.x * 256 + t) * GCNT_CHUNK;
    int cur = -1, run = 0;
#pragma unroll
    for (int u = 0; u < GCNT_CHUNK; u++) {
        int i = base + u;
        if (i < N_NODES) {
            int g = ld_idx(bat, i, sh);
            if (g == cur) run++;
            else { if (run) atomicAdd(&h[cur], run); cur = g; run = 1; }
        }
    }
    if (run) atomicAdd(&h[cur], run);
    __syncthreads();
    if (t < N_GRAPHS) { int v = h[t]; if (v) atomicAdd(&gcnt[t], v); }
}

// ---------------- GEMM-1: Y1[M,128] = X[M,256] @ W1 ----------------
// Block = 64 rows x FULL 128 cols (A read exactly once -> FETCH = ideal).
// A: one-shot global_load_lds stage (no VGPR round-trip), XOR-swizzled via
// pre-swizzled SOURCE address (linear LDS dest; rule: both-sides-or-neither).
// B: per-wave 32 cols register-resident, 16 x 1KB coalesced packed loads.
// One barrier total; stage latency hidden by 3+ independent blocks/CU.

__global__ __launch_bounds__(256) void k_gemm1(const void* __restrict__ Ain,
                                               const uint16_t* __restrict__ BF,  // W1F packed
                                               uint16_t* __restrict__ C,
                                               const int* __restrict__ flags) {
    __shared__ __align__(16) uint16_t As[64 * 256];   // 32 KB, swizzled, 16B-aligned
    const int M = N_NODES, N = HD1;
    int isbf = flags[0];
    int t = threadIdx.x;
    int wave = t >> 6, lane = t & 63;
    int quad = lane >> 4, l16 = lane & 15;
    int m0 = blockIdx.x * 64;
    int n0 = wave * 32;                               // wave's col group (n0g = wave)

    // B fragments: 16 x 1KB coalesced (L2-hot), issued before the stage
    bf16x8 Bf[8][2];
#pragma unroll
    for (int ks = 0; ks < 8; ks++)
#pragma unroll
        for (int nt = 0; nt < 2; nt++)
            Bf[ks][nt] = *(const bf16x8*)(BF + ((((wave * 8 + ks) * 2 + nt) << 6) + lane) * 8);

    // A-tile stage: 32 KB = 8 x (256 threads x 16B). LDS byte o holds logical
    // (r, c) with c = (o&511) ^ ((r&7)<<4)  -> read side applies the same XOR.
    if (isbf) {
        const uint8_t* Xb = (const uint8_t*)Ain;
#pragma unroll
        for (int i = 0; i < 8; i++) {
            int o = (i * 256 + t) * 16;
            int r = o >> 9, c = o & 511;
            int rg = m0 + r; if (rg >= M) rg = M - 1;
            gl_lds16(Xb + (size_t)rg * 512 + (c ^ ((r & 7) << 4)), (uint8_t*)As + o);
        }
    } else {
        const float* Xf = (const float*)Ain;
#pragma unroll
        for (int i = 0; i < 8; i++) {
            int o = (i * 256 + t) * 16;
            int r = o >> 9, c = (o & 511) ^ ((r & 7) << 4);
            int rg = m0 + r; if (rg >= M) rg = M - 1;
            const float* p = Xf + (size_t)rg * 256 + (c >> 1);
            f32x4 f0 = *(const f32x4*)p, f1 = *(const f32x4*)(p + 4);
            union { uint16_t u[8]; bf16x8 v; } rr;
#pragma unroll
            for (int j = 0; j < 4; j++) {
                rr.u[j]     = (uint16_t)f2bf_bits(f0[j]);
                rr.u[4 + j] = (uint16_t)f2bf_bits(f1[j]);
            }
            *(bf16x8*)((uint8_t*)As + o) = rr.v;
        }
    }
    __syncthreads();

    f32x4 acc[4][2];
#pragma unroll
    for (int a = 0; a < 4; a++)
#pragma unroll
        for (int b = 0; b < 2; b++) acc[a][b] = f32x4{0.f, 0.f, 0.f, 0.f};

#pragma unroll
    for (int ks = 0; ks < 8; ks++) {
        bf16x8 af[4];
#pragma unroll
        for (int mt = 0; mt < 4; mt++) {
            int r = mt * 16 + l16;
            int cb = (ks * 64 + quad * 16) ^ ((r & 7) << 4);
            af[mt] = *(const bf16x8*)((const uint8_t*)As + r * 512 + cb);
        }
#pragma unroll
        for (int mt = 0; mt < 4; mt++)
#pragma unroll
            for (int nt = 0; nt < 2; nt++)
                acc[mt][nt] = __builtin_amdgcn_mfma_f32_16x16x32_bf16(af[mt], Bf[ks][nt], acc[mt][nt], 0, 0, 0);
    }

#pragma unroll
    for (int mt = 0; mt < 4; mt++)
#pragma unroll
        for (int reg = 0; reg < 4; reg++) {
            int row = m0 + mt * 16 + quad * 4 + reg;  // C/D: col=lane&15, row=quad*4+reg
            if (row < M)
#pragma unroll
                for (int nt = 0; nt < 2; nt++)
                    C[row * N + n0 + nt * 16 + l16] = (uint16_t)f2bf_bits(acc[mt][nt][reg]);
        }
}

// ---------------- aggregation (wave-cooperative; readlane broadcast, 16-deep gather) ----------------
// out[d] = dinv[d] * (sum_src dinv[s]*Y[s] + dinv[d]*Y[d]) [+bias, relu]
// v_readlane (uniform index) -> SGPR src + scalar addressing: no ds_bpermute LDS-pipe traffic.
// (R5-verified form: 62 us/dispatch, the best of three measured variants.)

template <int WITH_BIAS_RELU>
__global__ __launch_bounds__(256) void k_agg(const uint16_t* __restrict__ Yin, uint16_t* __restrict__ Yout,
                                             const int* __restrict__ row_ptr, const int* __restrict__ csr_src,
                                             const float* __restrict__ dinv, const uint16_t* __restrict__ bias) {
    int node = blockIdx.x * 4 + (threadIdx.x >> 6);
    int l = threadIdx.x & 63;
    const uint32_t* Y32 = (const uint32_t*)Yin;

    float wd = dinv[node];
    uint32_t v = Y32[(size_t)node * 64 + l];
    float a0 = wd * bflo(v), a1 = wd * bfhi(v);

    int e0 = row_ptr[node], e1 = row_ptr[node + 1];
    for (int cb = e0; cb < e1; cb += 64) {
        int cnt = e1 - cb; if (cnt > 64) cnt = 64;
        // lane-parallel prefetch of indices + weights (1 coalesced load + 1 gather)
        int my_src = 0; uint32_t my_w = 0;            // lanes >= cnt: w=0 -> contribute 0, read row 0
        if (l < cnt) { my_src = csr_src[cb + l]; my_w = __float_as_uint(dinv[my_src]); }
        int rounds = (cnt + 15) >> 4;
        for (int r = 0; r < rounds; r++) {
            int jb = r * 16;
            uint32_t vv[16];
#pragma unroll
            for (int t = 0; t < 16; t++) {
                int s = __builtin_amdgcn_readlane(my_src, jb + t);   // SGPR: scalar addr math
                vv[t] = Y32[(size_t)s * 64 + l];
            }
#pragma unroll
            for (int t = 0; t < 16; t++) {
                float w = __uint_as_float(__builtin_amdgcn_readlane(my_w, jb + t));
                a0 += w * bflo(vv[t]);
                a1 += w * bfhi(vv[t]);
            }
        }
    }
    a0 *= wd; a1 *= wd;
    if (WITH_BIAS_RELU) {
        a0 = fmaxf(a0 + bf2f(bias[2 * l]), 0.f);
        a1 = fmaxf(a1 + bf2f(bias[2 * l + 1]), 0.f);
    }
    ((uint32_t*)Yout)[(size_t)node * 64 + l] = packbf(a0, a1);
}

// ---------------- FUSED agg-2 + GEMM-2 + bias/relu/pool ----------------
// Phase A: 8 waves aggregate 8 Z-rows each (identical gather loop + accumulation
// order as k_agg -> bitwise-same Z) straight into the swizzled LDS tile
// (ds_write_b32 at word (lane ^ ((r&7)<<2)): conflict-free, read-side compatible).
// Phase B: unchanged MFMA + pooled epilogue. Saves the 51 MB Zb round-trip.

__global__ __launch_bounds__(512) void k_gemm2_pool(const uint16_t* __restrict__ Hb,  // gather src [M][128]
                                                    const uint16_t* __restrict__ BF,  // W2F packed
                                                    const uint16_t* __restrict__ bias,// bc2 [256]
                                                    const int* __restrict__ bat,
                                                    const int* __restrict__ row_ptr,
                                                    const int* __restrict__ csr_src,
                                                    const float* __restrict__ dinv,
                                                    const int* __restrict__ flags,
                                                    float* __restrict__ pooled) {
    __shared__ __align__(16) uint16_t As[64 * 128];   // 16 KB, swizzled Z-tile
    const int M = N_NODES;
    int t = threadIdx.x;
    int wave = t >> 6, lane = t & 63;
    int quad = lane >> 4, l16 = lane & 15;
    int m0 = blockIdx.x * 64;
    int n0 = wave * 32;                               // 8 waves x 32 cols = 256

    bf16x8 Bf[4][2];
#pragma unroll
    for (int ks = 0; ks < 4; ks++)
#pragma unroll
        for (int nt = 0; nt < 2; nt++)
            Bf[ks][nt] = *(const bf16x8*)(BF + ((((wave * 4 + ks) * 2 + nt) << 6) + lane) * 8);

    // ---- Phase A: gather-aggregate 8 nodes per wave into LDS ----
    const uint32_t* Y32 = (const uint32_t*)Hb;
#pragma unroll 1
    for (int u = 0; u < 8; u++) {
        int node = m0 + wave * 8 + u;                 // wave-uniform
        float a0 = 0.f, a1 = 0.f;
        if (node < M) {
            float wd = dinv[node];
            uint32_t v = Y32[(size_t)node * 64 + lane];
            a0 = wd * bflo(v); a1 = wd * bfhi(v);
            int e0 = row_ptr[node], e1 = row_ptr[node + 1];
            for (int cb = e0; cb < e1; cb += 64) {
                int cnt = e1 - cb; if (cnt > 64) cnt = 64;
                int my_src = 0; uint32_t my_w = 0;
                if (lane < cnt) { my_src = csr_src[cb + lane]; my_w = __float_as_uint(dinv[my_src]); }
                int rounds = (cnt + 15) >> 4;
                for (int r = 0; r < rounds; r++) {
                    int jb = r * 16;
                    uint32_t vv[16];
#pragma unroll
                    for (int t2 = 0; t2 < 16; t2++) {
                        int s = __builtin_amdgcn_readlane(my_src, jb + t2);
                        vv[t2] = Y32[(size_t)s * 64 + lane];
                    }
#pragma unroll
                    for (int t2 = 0; t2 < 16; t2++) {
                        float w = __uint_as_float(__builtin_amdgcn_readlane(my_w, jb + t2));
                        a0 += w * bflo(vv[t2]);
                        a1 += w * bfhi(vv[t2]);
                    }
                }
            }
            a0 *= wd; a1 *= wd;
        }
        int r = wave * 8 + u;
        // swizzled LDS write: word index lane ^ ((r&7)<<2) == byte (lane*4)^((r&7)<<4)
        ((uint32_t*)As)[r * 64 + (lane ^ ((r & 7) << 2))] = packbf(a0, a1);
    }
    __syncthreads();

    // ---- Phase B: MFMA + pooled epilogue (unchanged) ----
    f32x4 acc[4][2];
#pragma unroll
    for (int a = 0; a < 4; a++)
#pragma unroll
        for (int b = 0; b < 2; b++) acc[a][b] = f32x4{0.f, 0.f, 0.f, 0.f};

#pragma unroll
    for (int ks = 0; ks < 4; ks++) {
        bf16x8 af[4];
#pragma unroll
        for (int mt = 0; mt < 4; mt++) {
            int r = mt * 16 + l16;
            int cb = (ks * 64 + quad * 16) ^ ((r & 7) << 4);
            af[mt] = *(const bf16x8*)((const uint8_t*)As + r * 256 + cb);
        }
#pragma unroll
        for (int mt = 0; mt < 4; mt++)
#pragma unroll
            for (int nt = 0; nt < 2; nt++)
                acc[mt][nt] = __builtin_amdgcn_mfma_f32_16x16x32_bf16(af[mt], Bf[ks][nt], acc[mt][nt], 0, 0, 0);
    }

    int sh = flags[1];
    float bv[2];
#pragma unroll
    for (int nt = 0; nt < 2; nt++) bv[nt] = bf2f(bias[n0 + nt * 16 + l16]);

    int last = m0 + 63 < M ? m0 + 63 : M - 1;
    int gfirst = ld_idx(bat, m0, sh);
    int glast  = ld_idx(bat, last, sh);
    if ((m0 + 63 < M) && gfirst == glast) {
        // all 64 rows valid, same graph: wave-local reduction, 1 atomic/col
#pragma unroll
        for (int nt = 0; nt < 2; nt++) {
            float s = 0.f;
#pragma unroll
            for (int mt = 0; mt < 4; mt++)
#pragma unroll
                for (int reg = 0; reg < 4; reg++)
                    s += fmaxf(acc[mt][nt][reg] + bv[nt], 0.f);
            s += __shfl_xor(s, 16);
            s += __shfl_xor(s, 32);
            if (quad == 0)
                atomicAdd(&pooled[gfirst * HD2 + n0 + nt * 16 + l16], s);
        }
    } else {
#pragma unroll
        for (int mt = 0; mt < 4; mt++) {
#pragma unroll
            for (int reg = 0; reg < 4; reg++) {
                int row = m0 + mt * 16 + quad * 4 + reg;
                if (row < M) {
                    int g = ld_idx(bat, row, sh);
#pragma unroll
                    for (int nt = 0; nt < 2; nt++)
                        atomicAdd(&pooled[g * HD2 + n0 + nt * 16 + l16],
                                  fmaxf(acc[mt][nt][reg] + bv[nt], 0.f));
                }
            }
        }
    }
}

// ---------------- final FC: out = relu(mean @ fcW + fcb), dual-dtype out ----------------

__global__ __launch_bounds__(512) void k_final(const float* __restrict__ pooled, const int* __restrict__ gcnt,
                                               const uint16_t* __restrict__ fcWc, const uint16_t* __restrict__ fcbc,
                                               void* __restrict__ out, const int* __restrict__ flags) {
    __shared__ float pm[HD2];
    int g = blockIdx.x, t = threadIdx.x;
    if (t < HD2) pm[t] = pooled[g * HD2 + t] / fmaxf((float)gcnt[g], 1.0f);
    __syncthreads();
    float acc = bf2f(fcbc[t]);
    for (int k = 0; k < HD2; k++) acc = fmaf(pm[k], bf2f(fcWc[k * OUT_DIM + t]), acc);
    acc = fmaxf(acc, 0.f);
    if (flags[0]) ((uint16_t*)out)[g * OUT_DIM + t] = (uint16_t)f2bf_bits(acc);
    else          ((float*)out)[g * OUT_DIM + t] = acc;
}

// ---------------- launcher ----------------

extern "C" void kernel_launch(void* const* d_in, const int* in_sizes, int n_in,
                              void* d_out, int out_size, void* d_ws, size_t ws_size,
                              hipStream_t stream) {
    const void* x   = d_in[0];               // [100000,256] bf16 or f32
    const int*  ei  = (const int*)d_in[1];   // [2,1600000] int32 or int64
    const int*  bat = (const int*)d_in[2];   // [100000]
    const void* W1  = d_in[3];               // [256,128]
    const void* b1  = d_in[4];               // [128]
    const void* W2  = d_in[5];               // [128,256]
    const void* b2  = d_in[6];               // [256]
    const void* fcW = d_in[7];               // [256,512]
    const void* fcb = d_in[8];               // [512]

    char* ws = (char*)d_ws;
    size_t off = 0;
    auto alloc = [&](size_t bytes) -> void* {
        void* p = ws + off;
        off += (bytes + 255) & ~(size_t)255;
        return p;
    };
    uint16_t* Y1   = (uint16_t*)alloc((size_t)N_NODES * HD1 * 2);
    uint16_t* Hb   = (uint16_t*)alloc((size_t)N_NODES * HD1 * 2);
    int*   row_ptr = (int*)alloc((N_NODES + 1) * 4);
    int*   csr_src = (int*)alloc((size_t)N_EDGES * 4);
    int*   tmp     = (int*)alloc((size_t)N_EDGES * 4);
    int*   bh      = (int*)alloc(NBLK * NBUCK * 4);
    int*   bhoff   = (int*)alloc(NBLK * NBUCK * 4);
    int*   bucket_cnt  = (int*)alloc(NBUCK * 4);
    int*   bucket_base = (int*)alloc((NBUCK + 1) * 4);
    float* dinv    = (float*)alloc(N_NODES * 4);
    int*   gcnt    = (int*)alloc(N_GRAPHS * 4);
    float* pooled  = (float*)alloc(N_GRAPHS * HD2 * 4);
    uint16_t* W1T  = (uint16_t*)alloc(IN_DIM * HD1 * 2);
    uint16_t* W2T  = (uint16_t*)alloc(HD1 * HD2 * 2);
    uint16_t* bc1  = (uint16_t*)alloc(HD1 * 2);
    uint16_t* bc2  = (uint16_t*)alloc(HD2 * 2);
    uint16_t* fcWc = (uint16_t*)alloc(HD2 * OUT_DIM * 2);
    uint16_t* fcbc = (uint16_t*)alloc(OUT_DIM * 2);
    int*   flags   = (int*)alloc(64 * 4);

    hipMemsetAsync(gcnt, 0, N_GRAPHS * 4, stream);
    hipMemsetAsync(pooled, 0, N_GRAPHS * HD2 * 4, stream);

    k_probe<<<1, 64, 0, stream>>>((const uint32_t*)x, ei, flags);

    // canonicalize weights/biases to bf16 (one fused kernel; W1/W2 fragment-packed)
    k_prep<<<(197504 + 255) / 256, 256, 0, stream>>>(W1, W2, fcW, b1, b2, fcb,
                                                     W1T, W2T, fcWc, bc1, bc2, fcbc, flags);

    // CSR build: hist -> colscan -> bscan -> part -> bucket sort (no global atomics)
    k_hist<<<NBLK, 256, 0, stream>>>(ei, bh, flags);
    k_colscan<<<NBUCK, 256, 0, stream>>>(bh, bhoff, bucket_cnt);
    k_bscan<<<1, 256, 0, stream>>>(bucket_cnt, bucket_base, row_ptr);
    k_part<<<NBLK, 256, 0, stream>>>(ei, bucket_base, bhoff, tmp, flags);
    k_bsort<<<NBUCK, 256, 0, stream>>>(tmp, bucket_base, csr_src, row_ptr, dinv);

    k_gcnt<<<(N_NODES + 256 * GCNT_CHUNK - 1) / (256 * GCNT_CHUNK), 256, 0, stream>>>(bat, gcnt, flags);

    // layer 1: Y1 = X @ W1 ; H = relu(A Y1 + b1)
    k_gemm1<<<(N_NODES + 63) / 64, 256, 0, stream>>>(x, W1T, Y1, flags);
    k_agg<1><<<N_NODES / 4, 256, 0, stream>>>(Y1, Hb, row_ptr, csr_src, dinv, bc1);

    // layer 2 fused: Z = A H (into LDS) ; pooled += relu(Z @ W2 + b2)
    k_gemm2_pool<<<(N_NODES + 63) / 64, 512, 0, stream>>>(Hb, W2T, bc2, bat,
                                                          row_ptr, csr_src, dinv, flags, pooled);

    // final FC
    k_final<<<N_GRAPHS, 512, 0, stream>>>(pooled, gcnt, fcWc, fcbc, d_out, flags);
}

// Round 10
// 400.557 us; speedup vs baseline: 1.0957x; 1.0471x over previous
//
#include <hip/hip_runtime.h>
#include <hip/hip_bf16.h>
#include <cstdint>

#define N_NODES 100000
#define N_EDGES 1600000
#define N_GRAPHS 64
#define IN_DIM 256
#define HD1 128
#define HD2 256
#define OUT_DIM 512

// CSR-build radix partition parameters
#define NBUCK 196          // ceil(100000/512) buckets of 512 dst nodes
#define NBLK  196          // edge-chunk blocks
#define EPB   8192         // edges per block (NBLK*EPB >= N_EDGES)

#define GB1   1563         // gemm1 blocks = ceil(100000/64)
#define GCNT_CHUNK 8
#define GCNT_BLKS 49       // ceil(100000 / (256*8))
#define PREP_BLKS 772      // ceil(197504/256)

typedef __bf16 bf16x8 __attribute__((ext_vector_type(8)));
typedef float f32x4 __attribute__((ext_vector_type(4)));

static __device__ __forceinline__ float bflo(uint32_t v) { return __uint_as_float(v << 16); }
static __device__ __forceinline__ float bfhi(uint32_t v) { return __uint_as_float(v & 0xffff0000u); }
static __device__ __forceinline__ uint32_t f2bf_bits(float f) {
    uint32_t u = __float_as_uint(f);
    return (u + 0x7fffu + ((u >> 16) & 1u)) >> 16;   // RNE
}
static __device__ __forceinline__ uint32_t packbf(float a, float b) {
    return f2bf_bits(a) | (f2bf_bits(b) << 16);
}
static __device__ __forceinline__ float bf2f(uint16_t b) { return __uint_as_float(((uint32_t)b) << 16); }

// direct global->LDS 16B copy (no VGPR round-trip)
static __device__ __forceinline__ void gl_lds16(const void* g, void* l) {
    __builtin_amdgcn_global_load_lds((const __attribute__((address_space(1))) uint32_t*)g,
                                     (__attribute__((address_space(3))) uint32_t*)l, 16, 0, 0);
}

// ---------------- runtime dtype probe ----------------
__global__ void k_probe(const uint32_t* __restrict__ xw, const int* __restrict__ ei,
                        int* __restrict__ flags) {
    if (threadIdx.x != 0 || blockIdx.x != 0) return;
    int mid = 0;
    for (int i = 0; i < 64; i++) {
        uint32_t f = (xw[i] >> 23) & 0xFF;
        if (f >= 64 && f < 200) mid++;
    }
    flags[0] = (mid < 32) ? 1 : 0;                  // bf16 vs f32
    int nz = 0;
    for (int i = 0; i < 64; i++) if (ei[2 * i + 1] != 0) nz++;
    flags[1] = (nz == 0) ? 1 : 0;                   // int64 vs int32
}

static __device__ __forceinline__ int ld_idx(const int* p, int i, int sh) { return p[i << sh]; }
static __device__ __forceinline__ float ld_f(const void* p, int i, int isbf) {
    return isbf ? bf2f(((const uint16_t*)p)[i]) : ((const float*)p)[i];
}

// ---------------- MERGED: weight canonicalization (prep) || edge histogram (hist) ----------------
// Independent work packed into one dispatch: blocks [0,772) prep, [772,968) hist.
// Bodies verbatim from the verified split kernels.
__global__ __launch_bounds__(256) void k_prep_hist(const void* __restrict__ W1, const void* __restrict__ W2,
                                                   const void* __restrict__ fcW, const void* __restrict__ b1,
                                                   const void* __restrict__ b2, const void* __restrict__ fcb,
                                                   uint16_t* __restrict__ W1F, uint16_t* __restrict__ W2F,
                                                   uint16_t* __restrict__ fcWc, uint16_t* __restrict__ bc1,
                                                   uint16_t* __restrict__ bc2, uint16_t* __restrict__ fcbc,
                                                   const int* __restrict__ ei, int* __restrict__ bh,
                                                   const int* __restrict__ flags) {
    __shared__ int h[NBUCK];
    if (blockIdx.x < PREP_BLKS) {
        int i = blockIdx.x * 256 + threadIdx.x;
        int isbf = flags[0];
        if (i < 32768) {                                   // W1F packed fragments
            int j = i & 7, l = (i >> 3) & 63, nt = (i >> 9) & 1, ks = (i >> 10) & 7, n0g = (i >> 13) & 3;
            int k = ks * 32 + (l >> 4) * 8 + j;
            int n = n0g * 32 + nt * 16 + (l & 15);
            W1F[i] = (uint16_t)f2bf_bits(ld_f(W1, k * HD1 + n, isbf));
        } else if (i < 65536) {                            // W2F packed fragments
            int j2 = i - 32768;
            int j = j2 & 7, l = (j2 >> 3) & 63, nt = (j2 >> 9) & 1, ks = (j2 >> 10) & 3, n0g = (j2 >> 12) & 7;
            int k = ks * 32 + (l >> 4) * 8 + j;
            int n = n0g * 32 + nt * 16 + (l & 15);
            W2F[j2] = (uint16_t)f2bf_bits(ld_f(W2, k * HD2 + n, isbf));
        } else if (i < 196608) {
            int j = i - 65536;
            fcWc[j] = (uint16_t)f2bf_bits(ld_f(fcW, j, isbf));
        } else if (i < 196736) {
            bc1[i - 196608] = (uint16_t)f2bf_bits(ld_f(b1, i - 196608, isbf));
        } else if (i < 196992) {
            bc2[i - 196736] = (uint16_t)f2bf_bits(ld_f(b2, i - 196736, isbf));
        } else if (i < 197504) {
            fcbc[i - 196992] = (uint16_t)f2bf_bits(ld_f(fcb, i - 196992, isbf));
        }
    } else {
        int t = threadIdx.x, blk = blockIdx.x - PREP_BLKS;
        if (t < NBUCK) h[t] = 0;
        __syncthreads();
        int sh = flags[1];
        int base = blk * EPB;
#pragma unroll
        for (int k = 0; k < EPB / 256; k++) {
            int e = base + k * 256 + t;
            if (e < N_EDGES) atomicAdd(&h[ld_idx(ei, N_EDGES + e, sh) >> 9], 1);
        }
        __syncthreads();
        if (t < NBUCK) bh[blk * NBUCK + t] = h[t];
    }
}

// ---------------- CSR build: scans + partition (verbatim) ----------------

__global__ __launch_bounds__(256) void k_colscan(const int* __restrict__ bh, int* __restrict__ bhoff,
                                                 int* __restrict__ bucket_cnt) {
    __shared__ int s[256];
    int b = blockIdx.x, t = threadIdx.x;
    int v = (t < NBLK) ? bh[t * NBUCK + b] : 0;
    s[t] = v; __syncthreads();
    for (int off = 1; off < 256; off <<= 1) {
        int x = (t >= off) ? s[t - off] : 0;
        __syncthreads();
        s[t] += x;
        __syncthreads();
    }
    if (t < NBLK) bhoff[t * NBUCK + b] = s[t] - v;    // exclusive within bucket
    if (t == 255) bucket_cnt[b] = s[255];
}

__global__ __launch_bounds__(256) void k_bscan(const int* __restrict__ bucket_cnt,
                                               int* __restrict__ bucket_base,
                                               int* __restrict__ row_ptr) {
    __shared__ int s[256];
    int t = threadIdx.x;
    int v = (t < NBUCK) ? bucket_cnt[t] : 0;
    s[t] = v; __syncthreads();
    for (int off = 1; off < 256; off <<= 1) {
        int x = (t >= off) ? s[t - off] : 0;
        __syncthreads();
        s[t] += x;
        __syncthreads();
    }
    if (t < NBUCK) bucket_base[t] = s[t] - v;
    if (t == NBUCK - 1) { bucket_base[NBUCK] = s[t]; row_ptr[N_NODES] = s[t]; }
}

__global__ __launch_bounds__(256) void k_part(const int* __restrict__ ei,
                                              const int* __restrict__ bucket_base,
                                              const int* __restrict__ bhoff,
                                              int* __restrict__ tmp,
                                              const int* __restrict__ flags) {
    __shared__ int cur[NBUCK];
    int t = threadIdx.x, blk = blockIdx.x;
    if (t < NBUCK) cur[t] = bucket_base[t] + bhoff[blk * NBUCK + t];
    __syncthreads();
    int sh = flags[1];
    int base = blk * EPB;
#pragma unroll
    for (int k = 0; k < EPB / 256; k++) {
        int e = base + k * 256 + t;
        if (e < N_EDGES) {
            int s = ld_idx(ei, e, sh), d = ld_idx(ei, N_EDGES + e, sh);
            int pos = atomicAdd(&cur[d >> 9], 1);
            tmp[pos] = (s << 9) | (d & 511);          // s<2^17 -> 26-bit key
        }
    }
}

// ---------------- MERGED: bucket sort (bsort) || GEMM-1 || per-graph counts (gcnt) ----------------
// Blocks [0,196) bsort, [196,196+1563) gemm1, [1759,1808) gcnt — independent
// work sharing one dispatch so bsort+gcnt hide under gemm1. One 32KB LDS
// buffer aliased per branch. Bodies verbatim from the verified split kernels.
__global__ __launch_bounds__(256) void k_merge1(const int* __restrict__ tmp,
                                                const int* __restrict__ bucket_base,
                                                int* __restrict__ csr_src,
                                                int* __restrict__ row_ptr,
                                                float* __restrict__ dinv,
                                                const void* __restrict__ Ain,
                                                const uint16_t* __restrict__ BF,
                                                uint16_t* __restrict__ C,
                                                const int* __restrict__ bat,
                                                int* __restrict__ gcnt,
                                                const int* __restrict__ flags) {
    __shared__ __align__(16) uint8_t lds[64 * 256 * 2];   // 32 KB shared pool
    int bx = blockIdx.x;
    if (bx < NBUCK) {
        // ---- bsort ----
        int* h = (int*)lds; int* a = h + 512; int* c = a + 512;
        int b = bx, t = threadIdx.x;
        int beg = bucket_base[b], end = bucket_base[b + 1];
        h[t] = 0; h[t + 256] = 0;
        __syncthreads();
        for (int i = beg + t; i < end; i += 256) atomicAdd(&h[tmp[i] & 511], 1);
        __syncthreads();
        a[t] = h[t]; a[t + 256] = h[t + 256];
        __syncthreads();
        for (int off = 1; off < 512; off <<= 1) {
            int x0 = (t >= off) ? a[t - off] : 0;
            int x1 = ((t + 256) >= off) ? a[t + 256 - off] : 0;
            __syncthreads();
            a[t] += x0; a[t + 256] += x1;
            __syncthreads();
        }
#pragma unroll
        for (int u = 0; u < 2; u++) {
            int i = t + u * 256;
            int node = (b << 9) + i;
            int ex = a[i] - h[i];
            if (node < N_NODES) {
                row_ptr[node] = beg + ex;
                dinv[node] = rsqrtf((float)(h[i] + 1));   // +1 self-loop
            }
            c[i] = ex;
        }
        __syncthreads();
        for (int i = beg + t; i < end; i += 256) {
            int e = tmp[i];
            int pos = atomicAdd(&c[e & 511], 1);
            csr_src[beg + pos] = e >> 9;
        }
    } else if (bx < NBUCK + GB1) {
        // ---- GEMM-1: Y1[M,128] = X[M,256] @ W1 (R5-verified body) ----
        uint16_t* As = (uint16_t*)lds;                    // 64 x 256, swizzled
        const int M = N_NODES, N = HD1;
        int isbf = flags[0];
        int t = threadIdx.x;
        int wave = t >> 6, lane = t & 63;
        int quad = lane >> 4, l16 = lane & 15;
        int bid = bx - NBUCK;
        int m0 = bid * 64;
        int n0 = wave * 32;                               // wave's col group (n0g = wave)

        bf16x8 Bf[8][2];
#pragma unroll
        for (int ks = 0; ks < 8; ks++)
#pragma unroll
            for (int nt = 0; nt < 2; nt++)
                Bf[ks][nt] = *(const bf16x8*)(BF + ((((wave * 8 + ks) * 2 + nt) << 6) + lane) * 8);

        if (isbf) {
            const uint8_t* Xb = (const uint8_t*)Ain;
#pragma unroll
            for (int i = 0; i < 8; i++) {
                int o = (i * 256 + t) * 16;
                int r = o >> 9, c = o & 511;
                int rg = m0 + r; if (rg >= M) rg = M - 1;
                gl_lds16(Xb + (size_t)rg * 512 + (c ^ ((r & 7) << 4)), (uint8_t*)As + o);
            }
        } else {
            const float* Xf = (const float*)Ain;
#pragma unroll
            for (int i = 0; i < 8; i++) {
                int o = (i * 256 + t) * 16;
                int r = o >> 9, c = (o & 511) ^ ((r & 7) << 4);
                int rg = m0 + r; if (rg >= M) rg = M - 1;
                const float* p = Xf + (size_t)rg * 256 + (c >> 1);
                f32x4 f0 = *(const f32x4*)p, f1 = *(const f32x4*)(p + 4);
                union { uint16_t u[8]; bf16x8 v; } rr;
#pragma unroll
                for (int j = 0; j < 4; j++) {
                    rr.u[j]     = (uint16_t)f2bf_bits(f0[j]);
                    rr.u[4 + j] = (uint16_t)f2bf_bits(f1[j]);
                }
                *(bf16x8*)((uint8_t*)As + o) = rr.v;
            }
        }
        __syncthreads();

        f32x4 acc[4][2];
#pragma unroll
        for (int a = 0; a < 4; a++)
#pragma unroll
            for (int b = 0; b < 2; b++) acc[a][b] = f32x4{0.f, 0.f, 0.f, 0.f};

#pragma unroll
        for (int ks = 0; ks < 8; ks++) {
            bf16x8 af[4];
#pragma unroll
            for (int mt = 0; mt < 4; mt++) {
                int r = mt * 16 + l16;
                int cb = (ks * 64 + quad * 16) ^ ((r & 7) << 4);
                af[mt] = *(const bf16x8*)((const uint8_t*)As + r * 512 + cb);
            }
#pragma unroll
            for (int mt = 0; mt < 4; mt++)
#pragma unroll
                for (int nt = 0; nt < 2; nt++)
                    acc[mt][nt] = __builtin_amdgcn_mfma_f32_16x16x32_bf16(af[mt], Bf[ks][nt], acc[mt][nt], 0, 0, 0);
        }

#pragma unroll
        for (int mt = 0; mt < 4; mt++)
#pragma unroll
            for (int reg = 0; reg < 4; reg++) {
                int row = m0 + mt * 16 + quad * 4 + reg;  // C/D: col=lane&15, row=quad*4+reg
                if (row < M)
#pragma unroll
                    for (int nt = 0; nt < 2; nt++)
                        C[row * N + n0 + nt * 16 + l16] = (uint16_t)f2bf_bits(acc[mt][nt][reg]);
            }
    } else {
        // ---- gcnt ----
        int* h = (int*)lds;
        int t = threadIdx.x;
        if (t < N_GRAPHS) h[t] = 0;
        __syncthreads();
        int sh = flags[1];
        int blk = bx - NBUCK - GB1;
        int base = (blk * 256 + t) * GCNT_CHUNK;
        int cur = -1, run = 0;
#pragma unroll
        for (int u = 0; u < GCNT_CHUNK; u++) {
            int i = base + u;
            if (i < N_NODES) {
                int g = ld_idx(bat, i, sh);
                if (g == cur) run++;
                else { if (run) atomicAdd(&h[cur], run); cur = g; run = 1; }
            }
        }
        if (run) atomicAdd(&h[cur], run);
        __syncthreads();
        if (t < N_GRAPHS) { int v = h[t]; if (v) atomicAdd(&gcnt[t], v); }
    }
}

// ---------------- aggregation (wave-cooperative; readlane broadcast, 16-deep gather) ----------------
// out[d] = dinv[d] * (sum_src dinv[s]*Y[s] + dinv[d]*Y[d]) [+bias, relu]
// (R5-verified form: 62 us/dispatch, best of three measured variants.)

template <int WITH_BIAS_RELU>
__global__ __launch_bounds__(256) void k_agg(const uint16_t* __restrict__ Yin, uint16_t* __restrict__ Yout,
                                             const int* __restrict__ row_ptr, const int* __restrict__ csr_src,
                                             const float* __restrict__ dinv, const uint16_t* __restrict__ bias) {
    int node = blockIdx.x * 4 + (threadIdx.x >> 6);
    int l = threadIdx.x & 63;
    const uint32_t* Y32 = (const uint32_t*)Yin;

    float wd = dinv[node];
    uint32_t v = Y32[(size_t)node * 64 + l];
    float a0 = wd * bflo(v), a1 = wd * bfhi(v);

    int e0 = row_ptr[node], e1 = row_ptr[node + 1];
    for (int cb = e0; cb < e1; cb += 64) {
        int cnt = e1 - cb; if (cnt > 64) cnt = 64;
        int my_src = 0; uint32_t my_w = 0;            // lanes >= cnt: w=0 -> contribute 0, read row 0
        if (l < cnt) { my_src = csr_src[cb + l]; my_w = __float_as_uint(dinv[my_src]); }
        int rounds = (cnt + 15) >> 4;
        for (int r = 0; r < rounds; r++) {
            int jb = r * 16;
            uint32_t vv[16];
#pragma unroll
            for (int t = 0; t < 16; t++) {
                int s = __builtin_amdgcn_readlane(my_src, jb + t);   // SGPR: scalar addr math
                vv[t] = Y32[(size_t)s * 64 + l];
            }
#pragma unroll
            for (int t = 0; t < 16; t++) {
                float w = __uint_as_float(__builtin_amdgcn_readlane(my_w, jb + t));
                a0 += w * bflo(vv[t]);
                a1 += w * bfhi(vv[t]);
            }
        }
    }
    a0 *= wd; a1 *= wd;
    if (WITH_BIAS_RELU) {
        a0 = fmaxf(a0 + bf2f(bias[2 * l]), 0.f);
        a1 = fmaxf(a1 + bf2f(bias[2 * l + 1]), 0.f);
    }
    ((uint32_t*)Yout)[(size_t)node * 64 + l] = packbf(a0, a1);
}

// ---------------- GEMM-2 + fused bias/relu/pool (R5-verified standalone) ----------------

__global__ __launch_bounds__(512) void k_gemm2_pool(const uint16_t* __restrict__ A,   // Zb [M][128]
                                                    const uint16_t* __restrict__ BF,  // W2F packed
                                                    const uint16_t* __restrict__ bias,// bc2 [256]
                                                    const int* __restrict__ bat,
                                                    const int* __restrict__ flags,
                                                    float* __restrict__ pooled) {
    __shared__ __align__(16) uint16_t As[64 * 128];   // 16 KB, swizzled, 16B-aligned
    const int M = N_NODES;
    int t = threadIdx.x;
    int wave = t >> 6, lane = t & 63;
    int quad = lane >> 4, l16 = lane & 15;
    int m0 = blockIdx.x * 64;
    int n0 = wave * 32;                               // 8 waves x 32 cols = 256

    bf16x8 Bf[4][2];
#pragma unroll
    for (int ks = 0; ks < 4; ks++)
#pragma unroll
        for (int nt = 0; nt < 2; nt++)
            Bf[ks][nt] = *(const bf16x8*)(BF + ((((wave * 4 + ks) * 2 + nt) << 6) + lane) * 8);

    // A-tile stage: 16 KB = 2 x (512 threads x 16B); Zb is always bf16
#pragma unroll
    for (int i = 0; i < 2; i++) {
        int o = (i * 512 + t) * 16;
        int r = o >> 8, c = o & 255;
        int rg = m0 + r; if (rg >= M) rg = M - 1;
        gl_lds16((const uint8_t*)A + (size_t)rg * 256 + (c ^ ((r & 7) << 4)), (uint8_t*)As + o);
    }
    __syncthreads();

    f32x4 acc[4][2];
#pragma unroll
    for (int a = 0; a < 4; a++)
#pragma unroll
        for (int b = 0; b < 2; b++) acc[a][b] = f32x4{0.f, 0.f, 0.f, 0.f};

#pragma unroll
    for (int ks = 0; ks < 4; ks++) {
        bf16x8 af[4];
#pragma unroll
        for (int mt = 0; mt < 4; mt++) {
            int r = mt * 16 + l16;
            int cb = (ks * 64 + quad * 16) ^ ((r & 7) << 4);
            af[mt] = *(const bf16x8*)((const uint8_t*)As + r * 256 + cb);
        }
#pragma unroll
        for (int mt = 0; mt < 4; mt++)
#pragma unroll
            for (int nt = 0; nt < 2; nt++)
                acc[mt][nt] = __builtin_amdgcn_mfma_f32_16x16x32_bf16(af[mt], Bf[ks][nt], acc[mt][nt], 0, 0, 0);
    }

    int sh = flags[1];
    float bv[2];
#pragma unroll
    for (int nt = 0; nt < 2; nt++) bv[nt] = bf2f(bias[n0 + nt * 16 + l16]);

    int last = m0 + 63 < M ? m0 + 63 : M - 1;
    int gfirst = ld_idx(bat, m0, sh);
    int glast  = ld_idx(bat, last, sh);
    if ((m0 + 63 < M) && gfirst == glast) {
#pragma unroll
        for (int nt = 0; nt < 2; nt++) {
            float s = 0.f;
#pragma unroll
            for (int mt = 0; mt < 4; mt++)
#pragma unroll
                for (int reg = 0; reg < 4; reg++)
                    s += fmaxf(acc[mt][nt][reg] + bv[nt], 0.f);
            s += __shfl_xor(s, 16);
            s += __shfl_xor(s, 32);
            if (quad == 0)
                atomicAdd(&pooled[gfirst * HD2 + n0 + nt * 16 + l16], s);
        }
    } else {
#pragma unroll
        for (int mt = 0; mt < 4; mt++) {
#pragma unroll
            for (int reg = 0; reg < 4; reg++) {
                int row = m0 + mt * 16 + quad * 4 + reg;
                if (row < M) {
                    int g = ld_idx(bat, row, sh);
#pragma unroll
                    for (int nt = 0; nt < 2; nt++)
                        atomicAdd(&pooled[g * HD2 + n0 + nt * 16 + l16],
                                  fmaxf(acc[mt][nt][reg] + bv[nt], 0.f));
                }
            }
        }
    }
}

// ---------------- final FC: out = relu(mean @ fcW + fcb), dual-dtype out ----------------

__global__ __launch_bounds__(512) void k_final(const float* __restrict__ pooled, const int* __restrict__ gcnt,
                                               const uint16_t* __restrict__ fcWc, const uint16_t* __restrict__ fcbc,
                                               void* __restrict__ out, const int* __restrict__ flags) {
    __shared__ float pm[HD2];
    int g = blockIdx.x, t = threadIdx.x;
    if (t < HD2) pm[t] = pooled[g * HD2 + t] / fmaxf((float)gcnt[g], 1.0f);
    __syncthreads();
    float acc = bf2f(fcbc[t]);
    for (int k = 0; k < HD2; k++) acc = fmaf(pm[k], bf2f(fcWc[k * OUT_DIM + t]), acc);
    acc = fmaxf(acc, 0.f);
    if (flags[0]) ((uint16_t*)out)[g * OUT_DIM + t] = (uint16_t)f2bf_bits(acc);
    else          ((float*)out)[g * OUT_DIM + t] = acc;
}

// ---------------- launcher ----------------

extern "C" void kernel_launch(void* const* d_in, const int* in_sizes, int n_in,
                              void* d_out, int out_size, void* d_ws, size_t ws_size,
                              hipStream_t stream) {
    const void* x   = d_in[0];               // [100000,256] bf16 or f32
    const int*  ei  = (const int*)d_in[1];   // [2,1600000] int32 or int64
    const int*  bat = (const int*)d_in[2];   // [100000]
    const void* W1  = d_in[3];               // [256,128]
    const void* b1  = d_in[4];               // [128]
    const void* W2  = d_in[5];               // [128,256]
    const void* b2  = d_in[6];               // [256]
    const void* fcW = d_in[7];               // [256,512]
    const void* fcb = d_in[8];               // [512]

    char* ws = (char*)d_ws;
    size_t off = 0;
    auto alloc = [&](size_t bytes) -> void* {
        void* p = ws + off;
        off += (bytes + 255) & ~(size_t)255;
        return p;
    };
    uint16_t* buf0 = (uint16_t*)alloc((size_t)N_NODES * HD1 * 2);   // Y1, later Zb
    uint16_t* Hb   = (uint16_t*)alloc((size_t)N_NODES * HD1 * 2);
    int*   row_ptr = (int*)alloc((N_NODES + 1) * 4);
    int*   csr_src = (int*)alloc((size_t)N_EDGES * 4);
    int*   tmp     = (int*)alloc((size_t)N_EDGES * 4);
    int*   bh      = (int*)alloc(NBLK * NBUCK * 4);
    int*   bhoff   = (int*)alloc(NBLK * NBUCK * 4);
    int*   bucket_cnt  = (int*)alloc(NBUCK * 4);
    int*   bucket_base = (int*)alloc((NBUCK + 1) * 4);
    float* dinv    = (float*)alloc(N_NODES * 4);
    int*   gcnt    = (int*)alloc(N_GRAPHS * 4);
    float* pooled  = (float*)alloc(N_GRAPHS * HD2 * 4);
    uint16_t* W1T  = (uint16_t*)alloc(IN_DIM * HD1 * 2);
    uint16_t* W2T  = (uint16_t*)alloc(HD1 * HD2 * 2);
    uint16_t* bc1  = (uint16_t*)alloc(HD1 * 2);
    uint16_t* bc2  = (uint16_t*)alloc(HD2 * 2);
    uint16_t* fcWc = (uint16_t*)alloc(HD2 * OUT_DIM * 2);
    uint16_t* fcbc = (uint16_t*)alloc(OUT_DIM * 2);
    int*   flags   = (int*)alloc(64 * 4);

    uint16_t* Y1 = buf0;
    uint16_t* Zb = buf0;   // Y1 dead after agg-1

    hipMemsetAsync(gcnt, 0, N_GRAPHS * 4, stream);
    hipMemsetAsync(pooled, 0, N_GRAPHS * HD2 * 4, stream);

    k_probe<<<1, 64, 0, stream>>>((const uint32_t*)x, ei, flags);

    // prep || hist (independent)
    k_prep_hist<<<PREP_BLKS + NBLK, 256, 0, stream>>>(W1, W2, fcW, b1, b2, fcb,
                                                      W1T, W2T, fcWc, bc1, bc2, fcbc,
                                                      ei, bh, flags);

    k_colscan<<<NBUCK, 256, 0, stream>>>(bh, bhoff, bucket_cnt);
    k_bscan<<<1, 256, 0, stream>>>(bucket_cnt, bucket_base, row_ptr);
    k_part<<<NBLK, 256, 0, stream>>>(ei, bucket_base, bhoff, tmp, flags);

    // bsort || gemm1 || gcnt (independent) — bsort+gcnt hide under gemm1
    k_merge1<<<NBUCK + GB1 + GCNT_BLKS, 256, 0, stream>>>(tmp, bucket_base, csr_src, row_ptr, dinv,
                                                          x, W1T, Y1, bat, gcnt, flags);

    // layer 1 aggregate: H = relu(A Y1 + b1)
    k_agg<1><<<N_NODES / 4, 256, 0, stream>>>(Y1, Hb, row_ptr, csr_src, dinv, bc1);

    // layer 2 (aggregate-first): Z = A H ; pooled += relu(Z @ W2 + b2)
    k_agg<0><<<N_NODES / 4, 256, 0, stream>>>(Hb, Zb, row_ptr, csr_src, dinv, nullptr);
    k_gemm2_pool<<<(N_NODES + 63) / 64, 512, 0, stream>>>(Zb, W2T, bc2, bat, flags, pooled);

    // final FC
    k_final<<<N_GRAPHS, 512, 0, stream>>>(pooled, gcnt, fcWc, fcbc, d_out, flags);
}